// Round 5
// baseline (918.452 us; speedup 1.0000x reference)
//
#include <hip/hip_runtime.h>
#include <hip/hip_fp16.h>

#define RES 512
#define NF 32

typedef float v2f __attribute__((ext_vector_type(2)));

static __device__ __forceinline__ float h2f(float v) {
    return __half2float(__float2half(v));
}
static __device__ __forceinline__ v2f mkv2(float a, float b) { v2f r; r.x = a; r.y = b; return r; }

// Quad-internal broadcast of lane L (0..3) via DPP quad_perm — pure VALU,
// no LDS pipe, no bank conflicts, bit-exact move.
template <int L>
static __device__ __forceinline__ float qb(float v) {
    return __int_as_float(__builtin_amdgcn_mov_dpp(
        __float_as_int(v), (L | (L << 2) | (L << 4) | (L << 6)), 0xf, 0xf, true));
}
// Quad sum (butterfly xor1 then xor2), fp32 value-level.
static __device__ __forceinline__ float qsum(float v) {
    v += __int_as_float(__builtin_amdgcn_mov_dpp(__float_as_int(v), 0xB1, 0xf, 0xf, true)); // [1,0,3,2]
    v += __int_as_float(__builtin_amdgcn_mov_dpp(__float_as_int(v), 0x4E, 0xf, 0xf, true)); // [2,3,0,1]
    return v;
}

#define GET(v, c) ((c) == 0 ? (v).x : ((c) == 1 ? (v).y : ((c) == 2 ? (v).z : (v).w)))

// FOUR LANES (one hardware quad) PER POINT. Lane q owns features/neurons
// G(q,t) = 4q + (t&3) + 16*(t>>2), t = 0..7 — i.e. cols {4q..4q+3} and
// {16+4q..16+4q+3}. This makes each quad's texel loads one contiguous 64B
// segment per row-chunk, and all cross-lane traffic quad-internal DPP
// (round-3 used ds_bpermute: 3.7e7 LDS bank-conflict cycles + lgkmcnt stalls).
//
// Exactness: y[j] (fp16 value decides every leaky-ReLU sign) is accumulated
// over ALL i = 0..31 ascending, sequentially, round-mul/round-add fp32 with
// contract off — identical per-accumulator op sequence to the passing kernel
// (packed v_pk ops are IEEE per-element, order preserved). h16[i]/m[j] are
// DPP-broadcast bit-exactly from their owner lane. o and n are 4-way
// tree-reduced fp32 partials — value-level, as in the passing round-3 kernel.
__global__ __launch_bounds__(256) void stylesdf_fused(
    const float* __restrict__ x,
    const float* __restrict__ planes,
    const float* __restrict__ W1,
    const float* __restrict__ b1,
    const float* __restrict__ W2,
    const float* __restrict__ b2,
    float* __restrict__ out, int N)
{
#pragma clang fp contract(off)
    __shared__ __align__(16) float sW1[NF * NF];   // fp16-valued W1*s, [i][j]
    __shared__ __align__(16) float sW1T[NF * NF];  // transposed [j][i]
    __shared__ __align__(16) float sW2[NF * 4];    // fp16-valued W2*s
    __shared__ __align__(16) float sB1[NF];
    __shared__ __align__(16) float sB2[4];
    __shared__ __align__(16) float sW2c0[NF];

    const float S16 = h2f(0.17677669529663687f);  // fp16(1/sqrt(32))
    const float LREL = h2f(0.2f);                 // fp16(0.2)

    const int tid = threadIdx.x;
    for (int idx = tid; idx < NF * NF; idx += 256) {
        float w = h2f(h2f(W1[idx]) * S16);  // fp16 multiply semantics
        sW1[idx] = w;
        sW1T[(idx & 31) * NF + (idx >> 5)] = w;
    }
    if (tid < NF * 4) sW2[tid] = h2f(h2f(W2[tid]) * S16);
    if (tid < NF) { sB1[tid] = h2f(b1[tid]); sW2c0[tid] = h2f(h2f(W2[tid * 4]) * S16); }
    if (tid < 4) sB2[tid] = h2f(b2[tid]);
    __syncthreads();

    const int gt = blockIdx.x * 256 + tid;
    const int p = gt >> 2;            // point index (uniform per quad)
    if (p >= N) return;               // whole quads drop together
    const int q = gt & 3;             // feature-quarter owned by this lane
    const int fq = q << 2;            // 4q: first col of this lane's low slice

    // ---- per-axis interp coordinates (identical ops to passing kernel) ----
    float fr0, fr1, fr2;
    int a0lo, a0hi, a1lo, a1hi, a2lo, a2hi;
#define AXIS(c, FR, LO, HI)                                 \
    {                                                       \
        float xt = (x[3 * p + (c)] + 1.0f) * 0.5f;          \
        float pos = xt * 511.0f;                            \
        float pf = floorf(pos);                             \
        FR = pos - pf;                                      \
        int qq = (int)pf;                                   \
        qq = qq < 0 ? 0 : (qq > 511 ? 511 : qq);            \
        LO = qq;                                            \
        HI = (qq + 1 > 511) ? 511 : qq + 1;                 \
    }
    AXIS(0, fr0, a0lo, a0hi)
    AXIS(1, fr1, a1lo, a1hi)
    AXIS(2, fr2, a2lo, a2hi)
#undef AXIS

    // element offsets of the 12 corner rows (plane bases stay in SGPRs)
    const int oA00 = (a0lo * RES + a1lo) << 5, oA01 = (a0lo * RES + a1hi) << 5;
    const int oA10 = (a0hi * RES + a1lo) << 5, oA11 = (a0hi * RES + a1hi) << 5;
    const int oB00 = (a0lo * RES + a2lo) << 5, oB01 = (a0lo * RES + a2hi) << 5;
    const int oB10 = (a0hi * RES + a2lo) << 5, oB11 = (a0hi * RES + a2hi) << 5;
    const int oC00 = (a1lo * RES + a2lo) << 5, oC01 = (a1lo * RES + a2hi) << 5;
    const int oC10 = (a1hi * RES + a2lo) << 5, oC11 = (a1hi * RES + a2hi) << 5;
    const float* pl0 = planes;
    const float* pl1 = planes + RES * RES * NF;
    const float* pl2 = planes + 2 * (RES * RES * NF);

#define LD4(b, off) (*(const float4*)((b) + (off)))

    const float ifa01 = 1.0f - fr0, ifb01 = 1.0f - fr1;  // plane0 axes (0,1)
    const float ifa02 = 1.0f - fr0, ifb02 = 1.0f - fr2;  // plane1 axes (0,2)
    const float ifa12 = 1.0f - fr1, ifb12 = 1.0f - fr2;  // plane2 axes (1,2)

    // ============ gather: this lane's 8 features, t = c + 4*kk ============
    float hl[8];                      // fp16-rounded h values (y-matvec input)
    float d0l[8], d1l[8], d2l[8];     // fp32 per-axis derivative values
    float4* ho = (float4*)(out + (size_t)N + (size_t)p * NF);

#pragma unroll
    for (int kk = 0; kk < 2; ++kk) {
        const int fo = fq + 16 * kk;  // quad covers one 64B segment per row
        const float4 vA00 = LD4(pl0, oA00 + fo), vA01 = LD4(pl0, oA01 + fo);
        const float4 vA10 = LD4(pl0, oA10 + fo), vA11 = LD4(pl0, oA11 + fo);
        const float4 vB00 = LD4(pl1, oB00 + fo), vB01 = LD4(pl1, oB01 + fo);
        const float4 vB10 = LD4(pl1, oB10 + fo), vB11 = LD4(pl1, oB11 + fo);
        const float4 vC00 = LD4(pl2, oC00 + fo), vC01 = LD4(pl2, oC01 + fo);
        const float4 vC10 = LD4(pl2, oC10 + fo), vC11 = LD4(pl2, oC11 + fo);
        float hc[4];
#pragma unroll
        for (int c = 0; c < 4; ++c) {
            const int f = 4 * kk + c;
            {  // plane 0, axes (0,1): bitwise h order: h = (h + t4) + t8
                const float a00 = GET(vA00, c), a01 = GET(vA01, c);
                const float a10 = GET(vA10, c), a11 = GET(vA11, c);
                const float t4 = (a00 * ifb01 + a01 * fr1) * ifa01;
                const float t8 = (a10 * ifb01 + a11 * fr1) * fr0;
                hc[c] = t4 + t8;  // (0+t4)+t8 == t4+t8 value-exact
                d0l[f] = (a10 - a00) * ifb01 + (a11 - a01) * fr1;
                d1l[f] = (a01 - a00) * ifa01 + (a11 - a10) * fr0;
            }
            {  // plane 1, axes (0,2)
                const float a00 = GET(vB00, c), a01 = GET(vB01, c);
                const float a10 = GET(vB10, c), a11 = GET(vB11, c);
                const float t4 = (a00 * ifb02 + a01 * fr2) * ifa02;
                const float t8 = (a10 * ifb02 + a11 * fr2) * fr0;
                hc[c] = (hc[c] + t4) + t8;
                d0l[f] += (a10 - a00) * ifb02 + (a11 - a01) * fr2;
                d2l[f] = (a01 - a00) * ifa02 + (a11 - a10) * fr0;
            }
            {  // plane 2, axes (1,2)
                const float a00 = GET(vC00, c), a01 = GET(vC01, c);
                const float a10 = GET(vC10, c), a11 = GET(vC11, c);
                const float t4 = (a00 * ifb12 + a01 * fr2) * ifa12;
                const float t8 = (a10 * ifb12 + a11 * fr2) * fr1;
                hc[c] = (hc[c] + t4) + t8;
                d1l[f] += (a10 - a00) * ifb12 + (a11 - a01) * fr2;
                d2l[f] += (a01 - a00) * ifa12 + (a11 - a10) * fr1;
            }
            hl[f] = h2f(hc[c]);  // h16
        }
        // fp32 h store, np order; quad writes contiguous 64B per kk
        ho[q + 4 * kk] = make_float4(hc[0], hc[1], hc[2], hc[3]);
    }

    // ====== y for this lane's 8 cols — EXACT i-sequential order, packed ======
    // y2[0]={j:4q,4q+1} y2[1]={4q+2,4q+3} y2[2]={16+4q,16+4q+1} y2[3]={+2,+3}
    v2f y2[4];
    y2[0] = mkv2(0.f, 0.f); y2[1] = mkv2(0.f, 0.f);
    y2[2] = mkv2(0.f, 0.f); y2[3] = mkv2(0.f, 0.f);

#define YSTEP(half, ow, e)                                                     \
    {                                                                          \
        const int i = 16 * (half) + 4 * (ow) + (e);                            \
        const float hi = qb<(ow)>(hl[(e) + 4 * (half)]);                       \
        const v2f hv = mkv2(hi, hi);                                           \
        const float4 wA = *(const float4*)(sW1 + i * NF + fq);                 \
        const float4 wB = *(const float4*)(sW1 + i * NF + fq + 16);            \
        y2[0] = y2[0] + hv * mkv2(wA.x, wA.y);  /* round mul, round add */     \
        y2[1] = y2[1] + hv * mkv2(wA.z, wA.w);                                 \
        y2[2] = y2[2] + hv * mkv2(wB.x, wB.y);                                 \
        y2[3] = y2[3] + hv * mkv2(wB.z, wB.w);                                 \
    }
#define Y4(half, ow) YSTEP(half, ow, 0) YSTEP(half, ow, 1) YSTEP(half, ow, 2) YSTEP(half, ow, 3)
#define Y16(half) Y4(half, 0) Y4(half, 1) Y4(half, 2) Y4(half, 3)
    Y16(0) Y16(1)
#undef Y16
#undef Y4
#undef YSTEP

    // ====== activations, layer-2 partials, m for this lane's cols ======
    float o0 = 0.f, o1 = 0.f, o2 = 0.f, o3 = 0.f;
    float ml[8];
#pragma unroll
    for (int t = 0; t < 8; ++t) {
        const int j = fq + (t & 3) + 16 * (t >> 2);
        const float yt = (t & 1) ? y2[t >> 1].y : y2[t >> 1].x;
        const float yd = h2f(yt);               // fp16 dot result
        const float y16 = h2f(yd + sB1[j]);     // fp16 bias add
        const bool nn = y16 >= 0.0f;
        const float zj = nn ? y16 : h2f(LREL * y16);  // fp16 leaky value
        const float4 w2 = ((const float4*)sW2)[j];
        o0 = o0 + zj * w2.x;  // per-lane fp32 partial (pre-round, value-level)
        o1 = o1 + zj * w2.y;
        o2 = o2 + zj * w2.z;
        o3 = o3 + zj * w2.w;
        ml[t] = (nn ? 1.0f : LREL) * sW2c0[j];
    }

    // ====== g for this lane's 8 rows — j ascending, packed fma ======
    v2f g2[4];
    g2[0] = mkv2(0.f, 0.f); g2[1] = mkv2(0.f, 0.f);
    g2[2] = mkv2(0.f, 0.f); g2[3] = mkv2(0.f, 0.f);

#define GSTEP(half, ow, e)                                                     \
    {                                                                          \
        const int j = 16 * (half) + 4 * (ow) + (e);                            \
        const float mj = qb<(ow)>(ml[(e) + 4 * (half)]);                       \
        const v2f mv = mkv2(mj, mj);                                           \
        const float4 wA = *(const float4*)(sW1T + j * NF + fq);                \
        const float4 wB = *(const float4*)(sW1T + j * NF + fq + 16);           \
        g2[0] = __builtin_elementwise_fma(mv, mkv2(wA.x, wA.y), g2[0]);        \
        g2[1] = __builtin_elementwise_fma(mv, mkv2(wA.z, wA.w), g2[1]);        \
        g2[2] = __builtin_elementwise_fma(mv, mkv2(wB.x, wB.y), g2[2]);        \
        g2[3] = __builtin_elementwise_fma(mv, mkv2(wB.z, wB.w), g2[3]);        \
    }
#define G4(half, ow) GSTEP(half, ow, 0) GSTEP(half, ow, 1) GSTEP(half, ow, 2) GSTEP(half, ow, 3)
#define G16(half) G4(half, 0) G4(half, 1) G4(half, 2) G4(half, 3)
    G16(0) G16(1)
#undef G16
#undef G4
#undef GSTEP

    // ====== nabla partials over this lane's rows, then quad tree add ======
    float n0 = 0.f, n1 = 0.f, n2 = 0.f;
#pragma unroll
    for (int t = 0; t < 8; ++t) {
        const float gt_ = (t & 1) ? g2[t >> 1].y : g2[t >> 1].x;
        n0 = fmaf(gt_, d0l[t], n0);
        n1 = fmaf(gt_, d1l[t], n1);
        n2 = fmaf(gt_, d2l[t], n2);
    }

    o0 = qsum(o0); o1 = qsum(o1); o2 = qsum(o2); o3 = qsum(o3);
    n0 = qsum(n0); n1 = qsum(n1); n2 = qsum(n2);

    // fp16 rounding of layer-2 output + bias
    o0 = h2f(h2f(o0) + sB2[0]);
    o1 = h2f(h2f(o1) + sB2[1]);
    o2 = h2f(h2f(o2) + sB2[2]);
    o3 = h2f(h2f(o3) + sB2[3]);
    n0 *= 511.0f; n1 *= 511.0f; n2 *= 511.0f;

    // ---- stores: one lane-role each ----
    if (q == 0) out[p] = o0;  // sdf
    if (q == 1) {
        const size_t nb = (size_t)N * 33 + (size_t)p * 3;
        out[nb + 0] = n0; out[nb + 1] = n1; out[nb + 2] = n2;
    }
    if (q == 2) {
        const size_t rb = (size_t)N * 36 + (size_t)p * 3;
        out[rb + 0] = (tanhf(o1) + 1.0f) * 0.5f;
        out[rb + 1] = (tanhf(o2) + 1.0f) * 0.5f;
        out[rb + 2] = (tanhf(o3) + 1.0f) * 0.5f;
    }
#undef LD4
#undef GET
}

extern "C" void kernel_launch(void* const* d_in, const int* in_sizes, int n_in,
                              void* d_out, int out_size, void* d_ws, size_t ws_size,
                              hipStream_t stream) {
    const float* x      = (const float*)d_in[0];
    const float* planes = (const float*)d_in[1];
    const float* W1     = (const float*)d_in[2];
    const float* b1     = (const float*)d_in[3];
    const float* W2     = (const float*)d_in[4];
    const float* b2     = (const float*)d_in[5];
    float* out = (float*)d_out;
    const int N = in_sizes[0] / 3;
    const long long total = 4LL * N;
    const int blocks = (int)((total + 255) / 256);
    stylesdf_fused<<<blocks, 256, 0, stream>>>(x, planes, W1, b1, W2, b2, out, N);
}

// Round 6
// 888.910 us; speedup vs baseline: 1.0332x; 1.0332x over previous
//
#include <hip/hip_runtime.h>
#include <hip/hip_fp16.h>

#define RES 512
#define NF 32

typedef float v2f __attribute__((ext_vector_type(2)));

static __device__ __forceinline__ float h2f(float v) {
    return __half2float(__float2half(v));
}
static __device__ __forceinline__ v2f mkv2(float a, float b) { v2f r; r.x = a; r.y = b; return r; }

// Quad-internal broadcast of lane L (0..3) via DPP quad_perm — pure VALU.
template <int L>
static __device__ __forceinline__ float qb(float v) {
    return __int_as_float(__builtin_amdgcn_mov_dpp(
        __float_as_int(v), (L | (L << 2) | (L << 4) | (L << 6)), 0xf, 0xf, true));
}
// Quad sum (butterfly xor1 then xor2), fp32 value-level.
static __device__ __forceinline__ float qsum(float v) {
    v += __int_as_float(__builtin_amdgcn_mov_dpp(__float_as_int(v), 0xB1, 0xf, 0xf, true)); // [1,0,3,2]
    v += __int_as_float(__builtin_amdgcn_mov_dpp(__float_as_int(v), 0x4E, 0xf, 0xf, true)); // [2,3,0,1]
    return v;
}

#define GET(v, c) ((c) == 0 ? (v).x : ((c) == 1 ? (v).y : ((c) == 2 ? (v).z : (v).w)))

// FOUR LANES (one hardware quad) PER POINT; lane q owns cols {4q..4q+3} and
// {16+4q..16+4q+3}. SINGLE fused matvec loop: per step i the shared W1 row
// read feeds BOTH the bitwise-exact forward y and the fp32 backward
// e_axis[j] = sum_i D_axis[i]*W1s[i][j] (round-1 formulation, passed), so the
// old G loop (64 ds_read_b128/thread), the sW1T transpose (whose 32-way
// scatter-write was the ENTIRE 3.25e7 SQ_LDS_BANK_CONFLICT — round 1 without
// it measured 0), and the ml array are all deleted. nabla folds into the
// activation loop: n_axis = sum_j m_j * e_axis[j]  (fp32 value-level).
//
// Exactness: y[j] (fp16 value decides every leaky-ReLU sign) is accumulated
// over ALL i = 0..31 ascending, sequentially, round-mul/round-add fp32 with
// contract off — identical per-accumulator op sequence to the passing kernel
// (packed v_pk ops are IEEE per-element; e-updates use explicit fma and touch
// only fp32 value-level outputs). h16[i]/D[i] are DPP-broadcast bit-exactly.
__global__ __launch_bounds__(256) void stylesdf_fused(
    const float* __restrict__ x,
    const float* __restrict__ planes,
    const float* __restrict__ W1,
    const float* __restrict__ b1,
    const float* __restrict__ W2,
    const float* __restrict__ b2,
    float* __restrict__ out, int N)
{
#pragma clang fp contract(off)
    __shared__ __align__(16) float sW1[NF * NF];   // fp16-valued W1*s, [i][j]
    __shared__ __align__(16) float sW2[NF * 4];    // fp16-valued W2*s
    __shared__ __align__(16) float sB1[NF];
    __shared__ __align__(16) float sB2[4];
    __shared__ __align__(16) float sW2c0[NF];

    const float S16 = h2f(0.17677669529663687f);  // fp16(1/sqrt(32))
    const float LREL = h2f(0.2f);                 // fp16(0.2)

    const int tid = threadIdx.x;
    for (int idx = tid; idx < NF * NF; idx += 256)
        sW1[idx] = h2f(h2f(W1[idx]) * S16);  // fp16 multiply semantics
    if (tid < NF * 4) sW2[tid] = h2f(h2f(W2[tid]) * S16);
    if (tid < NF) { sB1[tid] = h2f(b1[tid]); sW2c0[tid] = h2f(h2f(W2[tid * 4]) * S16); }
    if (tid < 4) sB2[tid] = h2f(b2[tid]);
    __syncthreads();

    const int gt = blockIdx.x * 256 + tid;
    const int p = gt >> 2;            // point index (uniform per quad)
    if (p >= N) return;               // whole quads drop together
    const int q = gt & 3;             // feature-quarter owned by this lane
    const int fq = q << 2;            // 4q: first col of this lane's low slice

    // ---- per-axis interp coordinates (identical ops to passing kernel) ----
    float fr0, fr1, fr2;
    int a0lo, a0hi, a1lo, a1hi, a2lo, a2hi;
#define AXIS(c, FR, LO, HI)                                 \
    {                                                       \
        float xt = (x[3 * p + (c)] + 1.0f) * 0.5f;          \
        float pos = xt * 511.0f;                            \
        float pf = floorf(pos);                             \
        FR = pos - pf;                                      \
        int qq = (int)pf;                                   \
        qq = qq < 0 ? 0 : (qq > 511 ? 511 : qq);            \
        LO = qq;                                            \
        HI = (qq + 1 > 511) ? 511 : qq + 1;                 \
    }
    AXIS(0, fr0, a0lo, a0hi)
    AXIS(1, fr1, a1lo, a1hi)
    AXIS(2, fr2, a2lo, a2hi)
#undef AXIS

    // element offsets of the 12 corner rows (plane bases stay in SGPRs)
    const int oA00 = (a0lo * RES + a1lo) << 5, oA01 = (a0lo * RES + a1hi) << 5;
    const int oA10 = (a0hi * RES + a1lo) << 5, oA11 = (a0hi * RES + a1hi) << 5;
    const int oB00 = (a0lo * RES + a2lo) << 5, oB01 = (a0lo * RES + a2hi) << 5;
    const int oB10 = (a0hi * RES + a2lo) << 5, oB11 = (a0hi * RES + a2hi) << 5;
    const int oC00 = (a1lo * RES + a2lo) << 5, oC01 = (a1lo * RES + a2hi) << 5;
    const int oC10 = (a1hi * RES + a2lo) << 5, oC11 = (a1hi * RES + a2hi) << 5;
    const float* pl0 = planes;
    const float* pl1 = planes + RES * RES * NF;
    const float* pl2 = planes + 2 * (RES * RES * NF);

#define LD4(b, off) (*(const float4*)((b) + (off)))

    const float ifa01 = 1.0f - fr0, ifb01 = 1.0f - fr1;  // plane0 axes (0,1)
    const float ifa02 = 1.0f - fr0, ifb02 = 1.0f - fr2;  // plane1 axes (0,2)
    const float ifa12 = 1.0f - fr1, ifb12 = 1.0f - fr2;  // plane2 axes (1,2)

    // ============ gather: this lane's 8 features, t = c + 4*kk ============
    float hl[8];                      // fp16-rounded h values (y-matvec input)
    float d0l[8], d1l[8], d2l[8];     // fp32 per-axis derivative values
    float4* ho = (float4*)(out + (size_t)N + (size_t)p * NF);

#pragma unroll
    for (int kk = 0; kk < 2; ++kk) {
        const int fo = fq + 16 * kk;  // quad covers one 64B segment per row
        const float4 vA00 = LD4(pl0, oA00 + fo), vA01 = LD4(pl0, oA01 + fo);
        const float4 vA10 = LD4(pl0, oA10 + fo), vA11 = LD4(pl0, oA11 + fo);
        const float4 vB00 = LD4(pl1, oB00 + fo), vB01 = LD4(pl1, oB01 + fo);
        const float4 vB10 = LD4(pl1, oB10 + fo), vB11 = LD4(pl1, oB11 + fo);
        const float4 vC00 = LD4(pl2, oC00 + fo), vC01 = LD4(pl2, oC01 + fo);
        const float4 vC10 = LD4(pl2, oC10 + fo), vC11 = LD4(pl2, oC11 + fo);
        float hc[4];
#pragma unroll
        for (int c = 0; c < 4; ++c) {
            const int f = 4 * kk + c;
            {  // plane 0, axes (0,1): bitwise h order: h = (h + t4) + t8
                const float a00 = GET(vA00, c), a01 = GET(vA01, c);
                const float a10 = GET(vA10, c), a11 = GET(vA11, c);
                const float t4 = (a00 * ifb01 + a01 * fr1) * ifa01;
                const float t8 = (a10 * ifb01 + a11 * fr1) * fr0;
                hc[c] = t4 + t8;  // (0+t4)+t8 == t4+t8 value-exact
                d0l[f] = (a10 - a00) * ifb01 + (a11 - a01) * fr1;
                d1l[f] = (a01 - a00) * ifa01 + (a11 - a10) * fr0;
            }
            {  // plane 1, axes (0,2)
                const float a00 = GET(vB00, c), a01 = GET(vB01, c);
                const float a10 = GET(vB10, c), a11 = GET(vB11, c);
                const float t4 = (a00 * ifb02 + a01 * fr2) * ifa02;
                const float t8 = (a10 * ifb02 + a11 * fr2) * fr0;
                hc[c] = (hc[c] + t4) + t8;
                d0l[f] += (a10 - a00) * ifb02 + (a11 - a01) * fr2;
                d2l[f] = (a01 - a00) * ifa02 + (a11 - a10) * fr0;
            }
            {  // plane 2, axes (1,2)
                const float a00 = GET(vC00, c), a01 = GET(vC01, c);
                const float a10 = GET(vC10, c), a11 = GET(vC11, c);
                const float t4 = (a00 * ifb12 + a01 * fr2) * ifa12;
                const float t8 = (a10 * ifb12 + a11 * fr2) * fr1;
                hc[c] = (hc[c] + t4) + t8;
                d1l[f] += (a10 - a00) * ifb12 + (a11 - a01) * fr2;
                d2l[f] += (a01 - a00) * ifa12 + (a11 - a10) * fr1;
            }
            hl[f] = h2f(hc[c]);  // h16
        }
        // fp32 h store, np order; quad writes contiguous 64B per kk
        ho[q + 4 * kk] = make_float4(hc[0], hc[1], hc[2], hc[3]);
    }

    // ====== FUSED matvec: y (bitwise i-sequential) + e0/e1/e2 (fp32) ======
    // slot layout for y2/e*: [0]={col 4q,4q+1} [1]={4q+2,4q+3}
    //                        [2]={16+4q,16+4q+1} [3]={16+4q+2,16+4q+3}
    v2f y2[4], e0v[4], e1v[4], e2v[4];
#pragma unroll
    for (int k = 0; k < 4; ++k) {
        y2[k] = mkv2(0.f, 0.f);
        e0v[k] = mkv2(0.f, 0.f); e1v[k] = mkv2(0.f, 0.f); e2v[k] = mkv2(0.f, 0.f);
    }

#define YSTEP(half, ow, e_)                                                    \
    {                                                                          \
        const int i_ = 16 * (half) + 4 * (ow) + (e_);                          \
        const int t_ = (e_) + 4 * (half);                                      \
        const float hi = qb<(ow)>(hl[t_]);                                     \
        const float dA = qb<(ow)>(d0l[t_]);                                    \
        const float dB = qb<(ow)>(d1l[t_]);                                    \
        const float dC = qb<(ow)>(d2l[t_]);                                    \
        const float4 wA = *(const float4*)(sW1 + i_ * NF + fq);                \
        const float4 wB = *(const float4*)(sW1 + i_ * NF + fq + 16);           \
        const v2f w0 = mkv2(wA.x, wA.y), w1 = mkv2(wA.z, wA.w);                \
        const v2f w2v = mkv2(wB.x, wB.y), w3 = mkv2(wB.z, wB.w);               \
        const v2f hv = mkv2(hi, hi);                                           \
        y2[0] = y2[0] + hv * w0;   /* round mul, round add (contract off) */   \
        y2[1] = y2[1] + hv * w1;                                               \
        y2[2] = y2[2] + hv * w2v;                                              \
        y2[3] = y2[3] + hv * w3;                                               \
        const v2f av = mkv2(dA, dA), bv = mkv2(dB, dB), cv = mkv2(dC, dC);     \
        e0v[0] = __builtin_elementwise_fma(av, w0, e0v[0]);                    \
        e0v[1] = __builtin_elementwise_fma(av, w1, e0v[1]);                    \
        e0v[2] = __builtin_elementwise_fma(av, w2v, e0v[2]);                   \
        e0v[3] = __builtin_elementwise_fma(av, w3, e0v[3]);                    \
        e1v[0] = __builtin_elementwise_fma(bv, w0, e1v[0]);                    \
        e1v[1] = __builtin_elementwise_fma(bv, w1, e1v[1]);                    \
        e1v[2] = __builtin_elementwise_fma(bv, w2v, e1v[2]);                   \
        e1v[3] = __builtin_elementwise_fma(bv, w3, e1v[3]);                    \
        e2v[0] = __builtin_elementwise_fma(cv, w0, e2v[0]);                    \
        e2v[1] = __builtin_elementwise_fma(cv, w1, e2v[1]);                    \
        e2v[2] = __builtin_elementwise_fma(cv, w2v, e2v[2]);                   \
        e2v[3] = __builtin_elementwise_fma(cv, w3, e2v[3]);                    \
    }
#define Y4(half, ow) YSTEP(half, ow, 0) YSTEP(half, ow, 1) YSTEP(half, ow, 2) YSTEP(half, ow, 3)
#define Y16(half) Y4(half, 0) Y4(half, 1) Y4(half, 2) Y4(half, 3)
    Y16(0) Y16(1)   // i = 0..31 strictly ascending
#undef Y16
#undef Y4
#undef YSTEP

    // ====== activations + layer-2 partials + nabla partials (fused) ======
    float o0 = 0.f, o1 = 0.f, o2 = 0.f, o3 = 0.f;
    float n0 = 0.f, n1 = 0.f, n2 = 0.f;
#pragma unroll
    for (int t = 0; t < 8; ++t) {
        const int j = fq + (t & 3) + 16 * (t >> 2);
        const float yt = (t & 1) ? y2[t >> 1].y : y2[t >> 1].x;
        const float yd = h2f(yt);               // fp16 dot result
        const float y16 = h2f(yd + sB1[j]);     // fp16 bias add
        const bool nn = y16 >= 0.0f;
        const float zj = nn ? y16 : h2f(LREL * y16);  // fp16 leaky value
        const float4 w2 = ((const float4*)sW2)[j];
        o0 = o0 + zj * w2.x;  // per-lane fp32 partial (pre-round, value-level)
        o1 = o1 + zj * w2.y;
        o2 = o2 + zj * w2.z;
        o3 = o3 + zj * w2.w;
        const float mj = (nn ? 1.0f : LREL) * sW2c0[j];
        const float ea = (t & 1) ? e0v[t >> 1].y : e0v[t >> 1].x;
        const float eb = (t & 1) ? e1v[t >> 1].y : e1v[t >> 1].x;
        const float ec = (t & 1) ? e2v[t >> 1].y : e2v[t >> 1].x;
        n0 = fmaf(mj, ea, n0);  // n_axis = sum_j m_j * e_axis[j]
        n1 = fmaf(mj, eb, n1);
        n2 = fmaf(mj, ec, n2);
    }

    o0 = qsum(o0); o1 = qsum(o1); o2 = qsum(o2); o3 = qsum(o3);
    n0 = qsum(n0); n1 = qsum(n1); n2 = qsum(n2);

    // fp16 rounding of layer-2 output + bias
    o0 = h2f(h2f(o0) + sB2[0]);
    o1 = h2f(h2f(o1) + sB2[1]);
    o2 = h2f(h2f(o2) + sB2[2]);
    o3 = h2f(h2f(o3) + sB2[3]);
    n0 *= 511.0f; n1 *= 511.0f; n2 *= 511.0f;

    // ---- stores: one lane-role each ----
    if (q == 0) out[p] = o0;  // sdf
    if (q == 1) {
        const size_t nb = (size_t)N * 33 + (size_t)p * 3;
        out[nb + 0] = n0; out[nb + 1] = n1; out[nb + 2] = n2;
    }
    if (q == 2) {
        const size_t rb = (size_t)N * 36 + (size_t)p * 3;
        out[rb + 0] = (tanhf(o1) + 1.0f) * 0.5f;
        out[rb + 1] = (tanhf(o2) + 1.0f) * 0.5f;
        out[rb + 2] = (tanhf(o3) + 1.0f) * 0.5f;
    }
#undef LD4
#undef GET
}

extern "C" void kernel_launch(void* const* d_in, const int* in_sizes, int n_in,
                              void* d_out, int out_size, void* d_ws, size_t ws_size,
                              hipStream_t stream) {
    const float* x      = (const float*)d_in[0];
    const float* planes = (const float*)d_in[1];
    const float* W1     = (const float*)d_in[2];
    const float* b1     = (const float*)d_in[3];
    const float* W2     = (const float*)d_in[4];
    const float* b2     = (const float*)d_in[5];
    float* out = (float*)d_out;
    const int N = in_sizes[0] / 3;
    const long long total = 4LL * N;
    const int blocks = (int)((total + 255) / 256);
    stylesdf_fused<<<blocks, 256, 0, stream>>>(x, planes, W1, b1, W2, b2, out, N);
}

// Round 8
// 882.894 us; speedup vs baseline: 1.0403x; 1.0068x over previous
//
#include <hip/hip_runtime.h>
#include <hip/hip_fp16.h>

#define RES 512
#define NF 32

typedef float v2f __attribute__((ext_vector_type(2)));
typedef float v4f __attribute__((ext_vector_type(4)));  // native vec for nontemporal builtins

static __device__ __forceinline__ float h2f(float v) {
    return __half2float(__float2half(v));
}
static __device__ __forceinline__ v2f mkv2(float a, float b) { v2f r; r.x = a; r.y = b; return r; }
static __device__ __forceinline__ v4f mkv4(float a, float b, float c, float d) {
    v4f r; r.x = a; r.y = b; r.z = c; r.w = d; return r;
}

// Quad-internal broadcast of lane L (0..3) via DPP quad_perm — pure VALU.
template <int L>
static __device__ __forceinline__ float qb(float v) {
    return __int_as_float(__builtin_amdgcn_mov_dpp(
        __float_as_int(v), (L | (L << 2) | (L << 4) | (L << 6)), 0xf, 0xf, true));
}
// Quad sum (butterfly xor1 then xor2), fp32 value-level.
static __device__ __forceinline__ float qsum(float v) {
    v += __int_as_float(__builtin_amdgcn_mov_dpp(__float_as_int(v), 0xB1, 0xf, 0xf, true)); // [1,0,3,2]
    v += __int_as_float(__builtin_amdgcn_mov_dpp(__float_as_int(v), 0x4E, 0xf, 0xf, true)); // [2,3,0,1]
    return v;
}

#define GET(v, c) ((c) == 0 ? (v).x : ((c) == 1 ? (v).y : ((c) == 2 ? (v).z : (v).w)))

// FOUR LANES (one hardware quad) PER POINT; lane q owns cols {4q..4q+3} and
// {16+4q..16+4q+3}. Round-5 two-loop structure (VGPR=64 -> 8 waves/SIMD; the
// round-6 fused loop hit 92 VGPR and halved occupancy) with two fixes:
//  1. sW1T built by TRANSPOSED GLOBAL READ + linear LDS write. Round 5's
//     LDS scatter-write ((idx&31)*NF+(idx>>5)) was the ENTIRE 3.25e7
//     SQ_LDS_BANK_CONFLICT (round-6 control without sW1T measured 0).
//     W1 is 4KB -> L1-resident; the global-side scatter is cheap.
//  2. Nontemporal stores for ALL output (h tile + sdf/nabla/rgb): output is
//     never re-read, and its 330MB of streaming writes was evicting the
//     100MB planes from L3 (FETCH_SIZE 1.5-1.9GB despite L3-sized planes).
//
// Exactness: y[j] (fp16 value decides every leaky-ReLU sign) is accumulated
// over ALL i = 0..31 ascending, sequentially, round-mul/round-add fp32 with
// contract off — identical per-accumulator op sequence to the passing kernel
// (packed v_pk ops are IEEE per-element, order preserved). h16[i]/m[j] are
// DPP-broadcast bit-exactly. o and n are 4-way tree-reduced fp32 partials —
// value-level, as in the passing round-3/5 kernels.
__global__ __launch_bounds__(256) void stylesdf_fused(
    const float* __restrict__ x,
    const float* __restrict__ planes,
    const float* __restrict__ W1,
    const float* __restrict__ b1,
    const float* __restrict__ W2,
    const float* __restrict__ b2,
    float* __restrict__ out, int N)
{
#pragma clang fp contract(off)
    __shared__ __align__(16) float sW1[NF * NF];   // fp16-valued W1*s, [i][j]
    __shared__ __align__(16) float sW1T[NF * NF];  // transposed [j][i]
    __shared__ __align__(16) float sW2[NF * 4];    // fp16-valued W2*s
    __shared__ __align__(16) float sB1[NF];
    __shared__ __align__(16) float sB2[4];
    __shared__ __align__(16) float sW2c0[NF];

    const float S16 = h2f(0.17677669529663687f);  // fp16(1/sqrt(32))
    const float LREL = h2f(0.2f);                 // fp16(0.2)

    const int tid = threadIdx.x;
    for (int idx = tid; idx < NF * NF; idx += 256) {
        sW1[idx] = h2f(h2f(W1[idx]) * S16);  // fp16 multiply semantics
        // transposed GLOBAL read (W1 is 4KB, L1-cached), LINEAR LDS write:
        // zero bank conflicts (the old LDS scatter-write was 3.25e7 cycles).
        sW1T[idx] = h2f(h2f(W1[(idx & 31) * NF + (idx >> 5)]) * S16);
    }
    if (tid < NF * 4) sW2[tid] = h2f(h2f(W2[tid]) * S16);
    if (tid < NF) { sB1[tid] = h2f(b1[tid]); sW2c0[tid] = h2f(h2f(W2[tid * 4]) * S16); }
    if (tid < 4) sB2[tid] = h2f(b2[tid]);
    __syncthreads();

    const int gt = blockIdx.x * 256 + tid;
    const int p = gt >> 2;            // point index (uniform per quad)
    if (p >= N) return;               // whole quads drop together
    const int q = gt & 3;             // feature-quarter owned by this lane
    const int fq = q << 2;            // 4q: first col of this lane's low slice

    // ---- per-axis interp coordinates (identical ops to passing kernel) ----
    float fr0, fr1, fr2;
    int a0lo, a0hi, a1lo, a1hi, a2lo, a2hi;
#define AXIS(c, FR, LO, HI)                                 \
    {                                                       \
        float xt = (x[3 * p + (c)] + 1.0f) * 0.5f;          \
        float pos = xt * 511.0f;                            \
        float pf = floorf(pos);                             \
        FR = pos - pf;                                      \
        int qq = (int)pf;                                   \
        qq = qq < 0 ? 0 : (qq > 511 ? 511 : qq);            \
        LO = qq;                                            \
        HI = (qq + 1 > 511) ? 511 : qq + 1;                 \
    }
    AXIS(0, fr0, a0lo, a0hi)
    AXIS(1, fr1, a1lo, a1hi)
    AXIS(2, fr2, a2lo, a2hi)
#undef AXIS

    // element offsets of the 12 corner rows (plane bases stay in SGPRs)
    const int oA00 = (a0lo * RES + a1lo) << 5, oA01 = (a0lo * RES + a1hi) << 5;
    const int oA10 = (a0hi * RES + a1lo) << 5, oA11 = (a0hi * RES + a1hi) << 5;
    const int oB00 = (a0lo * RES + a2lo) << 5, oB01 = (a0lo * RES + a2hi) << 5;
    const int oB10 = (a0hi * RES + a2lo) << 5, oB11 = (a0hi * RES + a2hi) << 5;
    const int oC00 = (a1lo * RES + a2lo) << 5, oC01 = (a1lo * RES + a2hi) << 5;
    const int oC10 = (a1hi * RES + a2lo) << 5, oC11 = (a1hi * RES + a2hi) << 5;
    const float* pl0 = planes;
    const float* pl1 = planes + RES * RES * NF;
    const float* pl2 = planes + 2 * (RES * RES * NF);

#define LD4(b, off) (*(const float4*)((b) + (off)))

    const float ifa01 = 1.0f - fr0, ifb01 = 1.0f - fr1;  // plane0 axes (0,1)
    const float ifa02 = 1.0f - fr0, ifb02 = 1.0f - fr2;  // plane1 axes (0,2)
    const float ifa12 = 1.0f - fr1, ifb12 = 1.0f - fr2;  // plane2 axes (1,2)

    // ============ gather: this lane's 8 features, t = c + 4*kk ============
    float hl[8];                      // fp16-rounded h values (y-matvec input)
    float d0l[8], d1l[8], d2l[8];     // fp32 per-axis derivative values
    v4f* ho = (v4f*)(out + (size_t)N + (size_t)p * NF);

#pragma unroll
    for (int kk = 0; kk < 2; ++kk) {
        const int fo = fq + 16 * kk;  // quad covers one 64B segment per row
        const float4 vA00 = LD4(pl0, oA00 + fo), vA01 = LD4(pl0, oA01 + fo);
        const float4 vA10 = LD4(pl0, oA10 + fo), vA11 = LD4(pl0, oA11 + fo);
        const float4 vB00 = LD4(pl1, oB00 + fo), vB01 = LD4(pl1, oB01 + fo);
        const float4 vB10 = LD4(pl1, oB10 + fo), vB11 = LD4(pl1, oB11 + fo);
        const float4 vC00 = LD4(pl2, oC00 + fo), vC01 = LD4(pl2, oC01 + fo);
        const float4 vC10 = LD4(pl2, oC10 + fo), vC11 = LD4(pl2, oC11 + fo);
        float hc[4];
#pragma unroll
        for (int c = 0; c < 4; ++c) {
            const int f = 4 * kk + c;
            {  // plane 0, axes (0,1): bitwise h order: h = (h + t4) + t8
                const float a00 = GET(vA00, c), a01 = GET(vA01, c);
                const float a10 = GET(vA10, c), a11 = GET(vA11, c);
                const float t4 = (a00 * ifb01 + a01 * fr1) * ifa01;
                const float t8 = (a10 * ifb01 + a11 * fr1) * fr0;
                hc[c] = t4 + t8;  // (0+t4)+t8 == t4+t8 value-exact
                d0l[f] = (a10 - a00) * ifb01 + (a11 - a01) * fr1;
                d1l[f] = (a01 - a00) * ifa01 + (a11 - a10) * fr0;
            }
            {  // plane 1, axes (0,2)
                const float a00 = GET(vB00, c), a01 = GET(vB01, c);
                const float a10 = GET(vB10, c), a11 = GET(vB11, c);
                const float t4 = (a00 * ifb02 + a01 * fr2) * ifa02;
                const float t8 = (a10 * ifb02 + a11 * fr2) * fr0;
                hc[c] = (hc[c] + t4) + t8;
                d0l[f] += (a10 - a00) * ifb02 + (a11 - a01) * fr2;
                d2l[f] = (a01 - a00) * ifa02 + (a11 - a10) * fr0;
            }
            {  // plane 2, axes (1,2)
                const float a00 = GET(vC00, c), a01 = GET(vC01, c);
                const float a10 = GET(vC10, c), a11 = GET(vC11, c);
                const float t4 = (a00 * ifb12 + a01 * fr2) * ifa12;
                const float t8 = (a10 * ifb12 + a11 * fr2) * fr1;
                hc[c] = (hc[c] + t4) + t8;
                d1l[f] += (a10 - a00) * ifb12 + (a11 - a01) * fr2;
                d2l[f] += (a01 - a00) * ifa12 + (a11 - a10) * fr1;
            }
            hl[f] = h2f(hc[c]);  // h16
        }
        // fp32 h store, np order; quad writes contiguous 64B per kk.
        // Nontemporal: output is never re-read — keep planes L3-resident.
        __builtin_nontemporal_store(mkv4(hc[0], hc[1], hc[2], hc[3]),
                                    &ho[q + 4 * kk]);
    }

    // ====== y for this lane's 8 cols — EXACT i-sequential order, packed ======
    // y2[0]={j:4q,4q+1} y2[1]={4q+2,4q+3} y2[2]={16+4q,16+4q+1} y2[3]={+2,+3}
    v2f y2[4];
    y2[0] = mkv2(0.f, 0.f); y2[1] = mkv2(0.f, 0.f);
    y2[2] = mkv2(0.f, 0.f); y2[3] = mkv2(0.f, 0.f);

#define YSTEP(half, ow, e)                                                     \
    {                                                                          \
        const int i = 16 * (half) + 4 * (ow) + (e);                            \
        const float hi = qb<(ow)>(hl[(e) + 4 * (half)]);                       \
        const v2f hv = mkv2(hi, hi);                                           \
        const float4 wA = *(const float4*)(sW1 + i * NF + fq);                 \
        const float4 wB = *(const float4*)(sW1 + i * NF + fq + 16);            \
        y2[0] = y2[0] + hv * mkv2(wA.x, wA.y);  /* round mul, round add */     \
        y2[1] = y2[1] + hv * mkv2(wA.z, wA.w);                                 \
        y2[2] = y2[2] + hv * mkv2(wB.x, wB.y);                                 \
        y2[3] = y2[3] + hv * mkv2(wB.z, wB.w);                                 \
    }
#define Y4(half, ow) YSTEP(half, ow, 0) YSTEP(half, ow, 1) YSTEP(half, ow, 2) YSTEP(half, ow, 3)
#define Y16(half) Y4(half, 0) Y4(half, 1) Y4(half, 2) Y4(half, 3)
    Y16(0) Y16(1)
#undef Y16
#undef Y4
#undef YSTEP

    // ====== activations, layer-2 partials, m for this lane's cols ======
    float o0 = 0.f, o1 = 0.f, o2 = 0.f, o3 = 0.f;
    float ml[8];
#pragma unroll
    for (int t = 0; t < 8; ++t) {
        const int j = fq + (t & 3) + 16 * (t >> 2);
        const float yt = (t & 1) ? y2[t >> 1].y : y2[t >> 1].x;
        const float yd = h2f(yt);               // fp16 dot result
        const float y16 = h2f(yd + sB1[j]);     // fp16 bias add
        const bool nn = y16 >= 0.0f;
        const float zj = nn ? y16 : h2f(LREL * y16);  // fp16 leaky value
        const float4 w2 = ((const float4*)sW2)[j];
        o0 = o0 + zj * w2.x;  // per-lane fp32 partial (pre-round, value-level)
        o1 = o1 + zj * w2.y;
        o2 = o2 + zj * w2.z;
        o3 = o3 + zj * w2.w;
        ml[t] = (nn ? 1.0f : LREL) * sW2c0[j];
    }

    // ====== g for this lane's 8 rows — j ascending, packed fma ======
    v2f g2[4];
    g2[0] = mkv2(0.f, 0.f); g2[1] = mkv2(0.f, 0.f);
    g2[2] = mkv2(0.f, 0.f); g2[3] = mkv2(0.f, 0.f);

#define GSTEP(half, ow, e)                                                     \
    {                                                                          \
        const int j = 16 * (half) + 4 * (ow) + (e);                            \
        const float mj = qb<(ow)>(ml[(e) + 4 * (half)]);                       \
        const v2f mv = mkv2(mj, mj);                                           \
        const float4 wA = *(const float4*)(sW1T + j * NF + fq);                \
        const float4 wB = *(const float4*)(sW1T + j * NF + fq + 16);           \
        g2[0] = __builtin_elementwise_fma(mv, mkv2(wA.x, wA.y), g2[0]);        \
        g2[1] = __builtin_elementwise_fma(mv, mkv2(wA.z, wA.w), g2[1]);        \
        g2[2] = __builtin_elementwise_fma(mv, mkv2(wB.x, wB.y), g2[2]);        \
        g2[3] = __builtin_elementwise_fma(mv, mkv2(wB.z, wB.w), g2[3]);        \
    }
#define G4(half, ow) GSTEP(half, ow, 0) GSTEP(half, ow, 1) GSTEP(half, ow, 2) GSTEP(half, ow, 3)
#define G16(half) G4(half, 0) G4(half, 1) G4(half, 2) G4(half, 3)
    G16(0) G16(1)
#undef G16
#undef G4
#undef GSTEP

    // ====== nabla partials over this lane's rows, then quad tree add ======
    float n0 = 0.f, n1 = 0.f, n2 = 0.f;
#pragma unroll
    for (int t = 0; t < 8; ++t) {
        const float gt_ = (t & 1) ? g2[t >> 1].y : g2[t >> 1].x;
        n0 = fmaf(gt_, d0l[t], n0);
        n1 = fmaf(gt_, d1l[t], n1);
        n2 = fmaf(gt_, d2l[t], n2);
    }

    o0 = qsum(o0); o1 = qsum(o1); o2 = qsum(o2); o3 = qsum(o3);
    n0 = qsum(n0); n1 = qsum(n1); n2 = qsum(n2);

    // fp16 rounding of layer-2 output + bias
    o0 = h2f(h2f(o0) + sB2[0]);
    o1 = h2f(h2f(o1) + sB2[1]);
    o2 = h2f(h2f(o2) + sB2[2]);
    o3 = h2f(h2f(o3) + sB2[3]);
    n0 *= 511.0f; n1 *= 511.0f; n2 *= 511.0f;

    // ---- stores: one lane-role each (nontemporal — never re-read) ----
    if (q == 0) __builtin_nontemporal_store(o0, &out[p]);  // sdf
    if (q == 1) {
        const size_t nb = (size_t)N * 33 + (size_t)p * 3;
        __builtin_nontemporal_store(n0, &out[nb + 0]);
        __builtin_nontemporal_store(n1, &out[nb + 1]);
        __builtin_nontemporal_store(n2, &out[nb + 2]);
    }
    if (q == 2) {
        const size_t rb = (size_t)N * 36 + (size_t)p * 3;
        __builtin_nontemporal_store((tanhf(o1) + 1.0f) * 0.5f, &out[rb + 0]);
        __builtin_nontemporal_store((tanhf(o2) + 1.0f) * 0.5f, &out[rb + 1]);
        __builtin_nontemporal_store((tanhf(o3) + 1.0f) * 0.5f, &out[rb + 2]);
    }
#undef LD4
#undef GET
}

extern "C" void kernel_launch(void* const* d_in, const int* in_sizes, int n_in,
                              void* d_out, int out_size, void* d_ws, size_t ws_size,
                              hipStream_t stream) {
    const float* x      = (const float*)d_in[0];
    const float* planes = (const float*)d_in[1];
    const float* W1     = (const float*)d_in[2];
    const float* b1     = (const float*)d_in[3];
    const float* W2     = (const float*)d_in[4];
    const float* b2     = (const float*)d_in[5];
    float* out = (float*)d_out;
    const int N = in_sizes[0] / 3;
    const long long total = 4LL * N;
    const int blocks = (int)((total + 255) / 256);
    stylesdf_fused<<<blocks, 256, 0, stream>>>(x, planes, W1, b1, W2, b2, out, N);
}